// Round 1
// baseline (155.751 us; speedup 1.0000x reference)
//
#include <hip/hip_runtime.h>

typedef __attribute__((ext_vector_type(8))) short short8;
typedef __attribute__((ext_vector_type(4))) float f32x4;

#define GROUP_ELEMS 2097152     // 2 channels * 64*128*128
#define NBLK 64

__device__ inline short f2bf(float f) {
  unsigned u = __builtin_bit_cast(unsigned, f);
  unsigned r = (u + 0x7FFFu + ((u >> 16) & 1u)) >> 16;
  return (short)r;
}

__global__ __launch_bounds__(256) void k1_partials(const float* __restrict__ x,
                                                   float2* __restrict__ partials) {
  int group = blockIdx.x >> 6;
  int blk = blockIdx.x & 63;
  const float4* p = (const float4*)(x + (size_t)group * GROUP_ELEMS + (size_t)blk * 32768);
  float sum = 0.f, sq = 0.f;
  for (int i = threadIdx.x; i < 8192; i += 256) {
    float4 v = p[i];
    sum += v.x + v.y + v.z + v.w;
    sq  += v.x*v.x + v.y*v.y + v.z*v.z + v.w*v.w;
  }
  for (int off = 32; off; off >>= 1) {
    sum += __shfl_down(sum, off, 64);
    sq  += __shfl_down(sq,  off, 64);
  }
  __shared__ float2 sw[4];
  int lane = threadIdx.x & 63, wid = threadIdx.x >> 6;
  if (lane == 0) sw[wid] = make_float2(sum, sq);
  __syncthreads();
  if (threadIdx.x == 0) {
    float s = 0.f, q = 0.f;
    for (int j = 0; j < 4; ++j) { s += sw[j].x; q += sw[j].y; }
    partials[blockIdx.x] = make_float2(s, q);
  }
}

__global__ void k2_stats(const float2* __restrict__ partials,
                         float2* __restrict__ stats, int* __restrict__ hist) {
  int t = threadIdx.x;
  if (t < 16) {
    float s = 0.f, q = 0.f;
    for (int j = 0; j < NBLK; ++j) { float2 p = partials[t * NBLK + j]; s += p.x; q += p.y; }
    float mean = s / (float)GROUP_ELEMS;
    float var  = q / (float)GROUP_ELEMS - mean * mean;
    stats[t] = make_float2(mean, rsqrtf(var + 1e-5f));
  }
  if (t < 21) hist[t] = 0;
}

// repack conv weights into per-lane MFMA B-fragment layout:
// fbw[(cc*64+lane)*8 + j] = bf16(W[oc=lane&15][ic=((lane>>4)&1)*8+j][kpos=2cc+(lane>>5)])
__global__ void k2b_wprep(const float* __restrict__ wgt, unsigned short* __restrict__ fbw) {
  int t = threadIdx.x;             // 896 = 14 cc * 64 lanes
  int cc = t >> 6, lane = t & 63;
  int m = lane & 15, g = lane >> 4;
  int icb = (g & 1) * 8, g2 = g >> 1;
  int kpos = 2 * cc + g2;
  short8 f;
  #pragma unroll
  for (int j = 0; j < 8; ++j)
    f[j] = (kpos <= 26) ? f2bf(wgt[m * 432 + (icb + j) * 27 + kpos]) : (short)0;
  *(short8*)(fbw + t * 8) = f;
}

// thread per (b, hw, channel-pair): 1024 blocks x 256 thr. Loops d with 2-deep
// prefetch. z written bf16 [b][d][hw][ic], packed 2ch per 4B store.
__global__ __launch_bounds__(256) void k3_norm_thresh_hist(
    const float* __restrict__ x, const float* __restrict__ gw, const float* __restrict__ gb,
    const float* __restrict__ thrp, const float2* __restrict__ stats,
    unsigned short* __restrict__ z, int* __restrict__ hist) {
  __shared__ int sh[21];
  int t = threadIdx.x;
  if (t < 21) sh[t] = 0;
  __syncthreads();
  int hwl = t & 31, cp = t >> 5;
  int b = blockIdx.x >> 9;
  int hw = (blockIdx.x & 511) * 32 + hwl;
  int c0 = cp * 2, c1 = c0 + 1;
  float2 st = stats[b * 8 + cp];
  float A0 = gw[c0] * st.y, B0 = gb[c0] - st.x * A0;
  float A1 = gw[c1] * st.y, B1 = gb[c1] - st.x * A1;
  float thr = thrp[0];
  const float* px0 = x + (size_t)(b * 16 + c0) * 1048576 + hw;
  const float* px1 = x + (size_t)(b * 16 + c1) * 1048576 + hw;
  unsigned* pz = (unsigned*)(z + ((size_t)b * 64 * 16384 + hw) * 16 + c0);
  int c10 = 0, c11 = 0, c12 = 0;
  float xv0 = px0[0], xv1 = px1[0];
  float yp0 = 0.f, yp1 = 0.f;
  for (int d = 0; d < 64; ++d) {
    float n0 = 0.f, n1 = 0.f;
    if (d < 63) { n0 = px0[(d + 1) * 16384]; n1 = px1[(d + 1) * 16384]; }
    float y0 = fmaxf(fmaf(xv0, A0, B0), 0.f);
    float y1 = fmaxf(fmaf(xv1, A1, B1), 0.f);
    float v0 = ceilf(0.5f * y0);
    if (v0 == 0.f) c10++; else if (v0 == 1.f) c11++; else if (v0 == 2.f) c12++;
    else if (v0 <= 10.f) atomicAdd(&sh[(int)v0 + 10], 1);
    float v1 = ceilf(0.5f * y1);
    if (v1 == 0.f) c10++; else if (v1 == 1.f) c11++; else if (v1 == 2.f) c12++;
    else if (v1 <= 10.f) atomicAdd(&sh[(int)v1 + 10], 1);
    float z0, z1;
    if (d == 0) { z0 = y0; z1 = y1; }
    else {
      float dd0 = (y0 - yp0) / thr;
      z0 = (fabsf(dd0) > 1.f) ? fmaf(dd0, thr, yp0) : yp0;
      float dd1 = (y1 - yp1) / thr;
      z1 = (fabsf(dd1) > 1.f) ? fmaf(dd1, thr, yp1) : yp1;
    }
    unsigned u = (unsigned)(unsigned short)f2bf(z0) | ((unsigned)(unsigned short)f2bf(z1) << 16);
    pz[d * 131072] = u;
    yp0 = y0; yp1 = y1;
    xv0 = n0; xv1 = n1;
  }
  atomicAdd(&sh[10], c10);
  atomicAdd(&sh[11], c11);
  atomicAdd(&sh[12], c12);
  __syncthreads();
  if (t < 21) atomicAdd(&hist[t], sh[t]);
}

// MFMA implicit-GEMM conv. Tile = 4d x 8h x 32w, 256 thr (4 waves).
// 4-plane LDS ring (43520 B -> 3 blocks/CU). T14 async-stage: issue next-plane
// global loads, compute 56 MFMA, ds_write, barrier. Weights from fbw (14
// coalesced 16B loads). dl fully unrolled -> static ring slots.
// T2 bank-conflict swizzle: 16B-granule select bit ig is XORed with bit2 of the
// w-position s (ig' = ig ^ ((s>>2)&1)). Without it, each quarter-wave phase of
// the A-read ds_read_b128 (16 lanes, stride 32 B) lands on only 4 of 8
// bank-groups (4 words/bank vs 2 ideal -> ~2x LDS pipe). With it, each phase
// covers all 8 groups exactly twice for every tap kw in {0,1,2}. Writes stay
// 64-consecutive-granule (conflict-free; pairs merely swap).
#define DT 4
__global__ __launch_bounds__(256, 3) void k4_conv(const unsigned short* __restrict__ z,
                                                  const unsigned short* __restrict__ fbw,
                                                  float* __restrict__ out) {
  __shared__ unsigned short lz[4 * 10 * 34 * 16];   // 43520 B
  const int t = threadIdx.x;
  const int lane = t & 63, wid = t >> 6;
  const int b = blockIdx.z;
  const int d0 = blockIdx.y * DT;
  const int h0 = (blockIdx.x >> 2) * 8, w0 = (blockIdx.x & 3) * 32;
  const int m = lane & 15, g = lane >> 4;
  const int icb = (g & 1) * 8;
  const bool gs = (g >= 2);
  // per-lane swizzle XOR constants for tap kw = 0,1,2 (ushort units, bit 3)
  const int xw0 = ((m >> 2) & 1) << 3;
  const int xw1 = (((m + 1) >> 2) & 1) << 3;
  const int xw2 = (((m + 2) >> 2) & 1) << 3;

  short8 fb[14];
  #pragma unroll
  for (int cc = 0; cc < 14; ++cc)
    fb[cc] = *(const short8*)(fbw + (cc * 64 + lane) * 8);

  const unsigned short* zb = z + (size_t)b * 64 * 16384 * 16;

  // prologue: stage planes ap=0..2 (global d = d0-1 .. d0+1)
  for (int gi = t; gi < 2040; gi += 256) {
    int ap = gi / 680;
    int r2 = gi - ap * 680;
    int r = r2 / 68;
    int rem = r2 - r * 68;
    int s = rem >> 1, ig = rem & 1;
    int dg = d0 - 1 + ap, hg = h0 - 1 + r, wg = w0 - 1 + s;
    short8 v = {0,0,0,0,0,0,0,0};
    if ((unsigned)dg < 64u && (unsigned)hg < 128u && (unsigned)wg < 128u)
      v = *(const short8*)(zb + ((size_t)dg * 16384 + hg * 128 + wg) * 16 + ig * 8);
    *(short8*)(&lz[((ap * 10 + r) * 34 + s) * 16 + (ig ^ ((s >> 2) & 1)) * 8]) = v;
  }
  __syncthreads();

  #pragma unroll
  for (int dl = 0; dl < DT; ++dl) {
    // T14 stage-issue: next plane ap=dl+3 -> ring slot (dl+3)&3 (disjoint from
    // compute(dl)'s slots {dl, dl+1, dl+2} & 3)
    short8 sv0 = {0,0,0,0,0,0,0,0}, sv1 = {0,0,0,0,0,0,0,0}, sv2 = {0,0,0,0,0,0,0,0};
    int so0 = 0, so1 = 0, so2 = -1;
    if (dl < DT - 1) {
      const int ap = dl + 3, sl = ap & 3;
      const int dg = d0 - 1 + ap;
      {
        int gi = t;
        int r = gi / 68, rem = gi - r * 68, s = rem >> 1, ig = rem & 1;
        int hg = h0 - 1 + r, wg = w0 - 1 + s;
        so0 = ((sl * 10 + r) * 34 + s) * 16 + (ig ^ ((s >> 2) & 1)) * 8;
        if ((unsigned)dg < 64u && (unsigned)hg < 128u && (unsigned)wg < 128u)
          sv0 = *(const short8*)(zb + ((size_t)dg * 16384 + hg * 128 + wg) * 16 + ig * 8);
      }
      {
        int gi = t + 256;
        int r = gi / 68, rem = gi - r * 68, s = rem >> 1, ig = rem & 1;
        int hg = h0 - 1 + r, wg = w0 - 1 + s;
        so1 = ((sl * 10 + r) * 34 + s) * 16 + (ig ^ ((s >> 2) & 1)) * 8;
        if ((unsigned)dg < 64u && (unsigned)hg < 128u && (unsigned)wg < 128u)
          sv1 = *(const short8*)(zb + ((size_t)dg * 16384 + hg * 128 + wg) * 16 + ig * 8);
      }
      if (t < 168) {
        int gi = t + 512;
        int r = gi / 68, rem = gi - r * 68, s = rem >> 1, ig = rem & 1;
        int hg = h0 - 1 + r, wg = w0 - 1 + s;
        so2 = ((sl * 10 + r) * 34 + s) * 16 + (ig ^ ((s >> 2) & 1)) * 8;
        if ((unsigned)dg < 64u && (unsigned)hg < 128u && (unsigned)wg < 128u)
          sv2 = *(const short8*)(zb + ((size_t)dg * 16384 + hg * 128 + wg) * 16 + ig * 8);
      }
    }
    // compute dl: 4 tiles per wave (hl = wid*2+(q>>1), wt = q&1), 14 MFMA each
    #pragma unroll
    for (int q = 0; q < 4; ++q) {
      const int hl = wid * 2 + (q >> 1), wt = q & 1;
      const int lb = (hl * 34 + wt * 16 + m) * 16 + icb;
      f32x4 acc = {0.f, 0.f, 0.f, 0.f};
      __builtin_amdgcn_s_setprio(1);
      #pragma unroll
      for (int cc = 0; cc < 14; ++cc) {
        const int kp0 = 2 * cc;
        const int kp1 = (2 * cc + 1 > 26) ? 26 : 2 * cc + 1;
        const int o0 = ((((dl + kp0 / 9) & 3) * 10 + (kp0 % 9) / 3) * 34 + (kp0 % 3)) * 16;
        const int o1 = ((((dl + kp1 / 9) & 3) * 10 + (kp1 % 9) / 3) * 34 + (kp1 % 3)) * 16;
        const int kw0 = kp0 % 3, kw1 = kp1 % 3;
        const int xa = (kw0 == 0) ? xw0 : (kw0 == 1) ? xw1 : xw2;
        const int xb_ = (kw1 == 0) ? xw0 : (kw1 == 1) ? xw1 : xw2;
        int off = (lb + (gs ? o1 : o0)) ^ (gs ? xb_ : xa);
        short8 a = *(const short8*)(&lz[off]);
        acc = __builtin_amdgcn_mfma_f32_16x16x32_bf16(a, fb[cc], acc, 0, 0, 0);
      }
      __builtin_amdgcn_s_setprio(0);
      float* op = out + (((size_t)(b * 16 + m) * 64 + (d0 + dl)) * 128 + (h0 + hl)) * 128
                  + w0 + wt * 16 + g * 4;
      *(float4*)op = make_float4(acc[0], acc[1], acc[2], acc[3]);
    }
    if (dl < DT - 1) {
      *(short8*)(&lz[so0]) = sv0;
      *(short8*)(&lz[so1]) = sv1;
      if (so2 >= 0) *(short8*)(&lz[so2]) = sv2;
      __syncthreads();
    }
  }
}

__global__ void k5_hist_out(const int* __restrict__ hist, float* __restrict__ out) {
  int t = threadIdx.x;
  if (t < 21) out[33554432u + t] = (float)hist[t] * (100.0f / 33554432.0f);
}

extern "C" void kernel_launch(void* const* d_in, const int* in_sizes, int n_in,
                              void* d_out, int out_size, void* d_ws, size_t ws_size,
                              hipStream_t stream) {
  (void)in_sizes; (void)n_in; (void)out_size; (void)ws_size;
  const float* x   = (const float*)d_in[0];
  const float* gw  = (const float*)d_in[1];
  const float* gb  = (const float*)d_in[2];
  const float* thr = (const float*)d_in[3];
  const float* cw  = (const float*)d_in[4];
  float* out = (float*)d_out;

  char* ws = (char*)d_ws;
  unsigned short* z = (unsigned short*)ws;                            // 64 MiB bf16
  float2* partials = (float2*)(ws + (size_t)67108864);                // 8 KiB
  float2* stats    = (float2*)(ws + (size_t)67108864 + 8192);         // 128 B
  int*    hist     = (int*)  (ws + (size_t)67108864 + 8192 + 128);    // 84 B
  unsigned short* fbw = (unsigned short*)(ws + (size_t)67108864 + 16384); // 14336 B

  k1_partials<<<1024, 256, 0, stream>>>(x, partials);
  k2_stats<<<1, 64, 0, stream>>>(partials, stats, hist);
  k2b_wprep<<<1, 896, 0, stream>>>(cw, fbw);
  k3_norm_thresh_hist<<<1024, 256, 0, stream>>>(x, gw, gb, thr, stats, z, hist);
  k4_conv<<<dim3(64, 16, 2), 256, 0, stream>>>(z, fbw, out);
  k5_hist_out<<<1, 64, 0, stream>>>(hist, out);
}

// Round 2
// 141.659 us; speedup vs baseline: 1.0995x; 1.0995x over previous
//
#include <hip/hip_runtime.h>

typedef __attribute__((ext_vector_type(8))) short short8;
typedef __attribute__((ext_vector_type(4))) float f32x4;

#define GROUP_ELEMS 2097152     // 2 channels * 64*128*128
#define NBLK 64

__device__ inline short f2bf(float f) {
  unsigned u = __builtin_bit_cast(unsigned, f);
  unsigned r = (u + 0x7FFFu + ((u >> 16) & 1u)) >> 16;
  return (short)r;
}

__global__ __launch_bounds__(256) void k1_partials(const float* __restrict__ x,
                                                   float2* __restrict__ partials) {
  int group = blockIdx.x >> 6;
  int blk = blockIdx.x & 63;
  const float4* p = (const float4*)(x + (size_t)group * GROUP_ELEMS + (size_t)blk * 32768);
  float sum = 0.f, sq = 0.f;
  for (int i = threadIdx.x; i < 8192; i += 256) {
    float4 v = p[i];
    sum += v.x + v.y + v.z + v.w;
    sq  += v.x*v.x + v.y*v.y + v.z*v.z + v.w*v.w;
  }
  for (int off = 32; off; off >>= 1) {
    sum += __shfl_down(sum, off, 64);
    sq  += __shfl_down(sq,  off, 64);
  }
  __shared__ float2 sw[4];
  int lane = threadIdx.x & 63, wid = threadIdx.x >> 6;
  if (lane == 0) sw[wid] = make_float2(sum, sq);
  __syncthreads();
  if (threadIdx.x == 0) {
    float s = 0.f, q = 0.f;
    for (int j = 0; j < 4; ++j) { s += sw[j].x; q += sw[j].y; }
    partials[blockIdx.x] = make_float2(s, q);
  }
}

__global__ void k2_stats(const float2* __restrict__ partials,
                         float2* __restrict__ stats, int* __restrict__ hist) {
  int t = threadIdx.x;
  if (t < 16) {
    float s = 0.f, q = 0.f;
    for (int j = 0; j < NBLK; ++j) { float2 p = partials[t * NBLK + j]; s += p.x; q += p.y; }
    float mean = s / (float)GROUP_ELEMS;
    float var  = q / (float)GROUP_ELEMS - mean * mean;
    stats[t] = make_float2(mean, rsqrtf(var + 1e-5f));
  }
  if (t < 21) hist[t] = 0;
}

// repack conv weights into per-lane MFMA B-fragment layout:
// fbw[(cc*64+lane)*8 + j] = bf16(W[oc=lane&15][ic=((lane>>4)&1)*8+j][kpos=2cc+(lane>>5)])
__global__ void k2b_wprep(const float* __restrict__ wgt, unsigned short* __restrict__ fbw) {
  int t = threadIdx.x;             // 896 = 14 cc * 64 lanes
  int cc = t >> 6, lane = t & 63;
  int m = lane & 15, g = lane >> 4;
  int icb = (g & 1) * 8, g2 = g >> 1;
  int kpos = 2 * cc + g2;
  short8 f;
  #pragma unroll
  for (int j = 0; j < 8; ++j)
    f[j] = (kpos <= 26) ? f2bf(wgt[m * 432 + (icb + j) * 27 + kpos]) : (short)0;
  *(short8*)(fbw + t * 8) = f;
}

// thread per (b, hw, channel-pair): 1024 blocks x 256 thr. Loops d with 2-deep
// prefetch. z written bf16 [b][d][hw][ic], packed 2ch per 4B store.
__global__ __launch_bounds__(256) void k3_norm_thresh_hist(
    const float* __restrict__ x, const float* __restrict__ gw, const float* __restrict__ gb,
    const float* __restrict__ thrp, const float2* __restrict__ stats,
    unsigned short* __restrict__ z, int* __restrict__ hist) {
  __shared__ int sh[21];
  int t = threadIdx.x;
  if (t < 21) sh[t] = 0;
  __syncthreads();
  int hwl = t & 31, cp = t >> 5;
  int b = blockIdx.x >> 9;
  int hw = (blockIdx.x & 511) * 32 + hwl;
  int c0 = cp * 2, c1 = c0 + 1;
  float2 st = stats[b * 8 + cp];
  float A0 = gw[c0] * st.y, B0 = gb[c0] - st.x * A0;
  float A1 = gw[c1] * st.y, B1 = gb[c1] - st.x * A1;
  float thr = thrp[0];
  const float* px0 = x + (size_t)(b * 16 + c0) * 1048576 + hw;
  const float* px1 = x + (size_t)(b * 16 + c1) * 1048576 + hw;
  unsigned* pz = (unsigned*)(z + ((size_t)b * 64 * 16384 + hw) * 16 + c0);
  int c10 = 0, c11 = 0, c12 = 0;
  float xv0 = px0[0], xv1 = px1[0];
  float yp0 = 0.f, yp1 = 0.f;
  for (int d = 0; d < 64; ++d) {
    float n0 = 0.f, n1 = 0.f;
    if (d < 63) { n0 = px0[(d + 1) * 16384]; n1 = px1[(d + 1) * 16384]; }
    float y0 = fmaxf(fmaf(xv0, A0, B0), 0.f);
    float y1 = fmaxf(fmaf(xv1, A1, B1), 0.f);
    float v0 = ceilf(0.5f * y0);
    if (v0 == 0.f) c10++; else if (v0 == 1.f) c11++; else if (v0 == 2.f) c12++;
    else if (v0 <= 10.f) atomicAdd(&sh[(int)v0 + 10], 1);
    float v1 = ceilf(0.5f * y1);
    if (v1 == 0.f) c10++; else if (v1 == 1.f) c11++; else if (v1 == 2.f) c12++;
    else if (v1 <= 10.f) atomicAdd(&sh[(int)v1 + 10], 1);
    float z0, z1;
    if (d == 0) { z0 = y0; z1 = y1; }
    else {
      float dd0 = (y0 - yp0) / thr;
      z0 = (fabsf(dd0) > 1.f) ? fmaf(dd0, thr, yp0) : yp0;
      float dd1 = (y1 - yp1) / thr;
      z1 = (fabsf(dd1) > 1.f) ? fmaf(dd1, thr, yp1) : yp1;
    }
    unsigned u = (unsigned)(unsigned short)f2bf(z0) | ((unsigned)(unsigned short)f2bf(z1) << 16);
    pz[d * 131072] = u;
    yp0 = y0; yp1 = y1;
    xv0 = n0; xv1 = n1;
  }
  atomicAdd(&sh[10], c10);
  atomicAdd(&sh[11], c11);
  atomicAdd(&sh[12], c12);
  __syncthreads();
  if (t < 21) atomicAdd(&hist[t], sh[t]);
}

// MFMA implicit-GEMM conv. Tile = 8d x 8h x 32w, 256 thr (4 waves).
// 3-plane LDS ring (32640 B): compute dl reads planes dl..dl+2 (all 3 slots);
// plane dl+3 overwrites plane dl's slot AFTER the compute barrier.
// T14 async-stage preserved: global loads issued before compute, ds_write after
// the first barrier, second barrier before next compute.
// Occupancy: 32640 B -> 4 blocks/CU resident (grid 1024 = exactly 4/CU).
// Swizzle: granule-half bit ig XORed with bit2 of w-position s (both sides).
#define DT 8
#define PLANE 5440          // 10*34*16 ushorts = 10880 B
__global__ __launch_bounds__(256, 4) void k4_conv(const unsigned short* __restrict__ z,
                                                  const unsigned short* __restrict__ fbw,
                                                  float* __restrict__ out) {
  __shared__ unsigned short lz[3 * PLANE];   // 32640 B
  const int t = threadIdx.x;
  const int lane = t & 63, wid = t >> 6;
  const int b = blockIdx.z;
  const int d0 = blockIdx.y * DT;
  const int h0 = (blockIdx.x >> 2) * 8, w0 = (blockIdx.x & 3) * 32;
  const int m = lane & 15, g = lane >> 4;
  const int icb = (g & 1) * 8;
  const bool gs = (g >= 2);
  // per-lane swizzle XOR constants for tap kw = 0,1,2 (ushort units, bit 3)
  const int xw0 = ((m >> 2) & 1) << 3;
  const int xw1 = (((m + 1) >> 2) & 1) << 3;
  const int xw2 = (((m + 2) >> 2) & 1) << 3;

  short8 fb[14];
  #pragma unroll
  for (int cc = 0; cc < 14; ++cc)
    fb[cc] = *(const short8*)(fbw + (cc * 64 + lane) * 8);

  const unsigned short* zb = z + (size_t)b * 16777216;   // 64*16384*16

  // per-thread staging coords (dl-invariant). chunk i handles granule
  // gi = t + 256*i within a 680-granule plane (10 rows x 34 s x 2 halves).
  const int gi0 = t,        r0 = gi0 / 68, rm0 = gi0 - r0 * 68, s0 = rm0 >> 1, ig0 = rm0 & 1;
  const int gi1 = t + 256,  r1 = gi1 / 68, rm1 = gi1 - r1 * 68, s1 = rm1 >> 1, ig1 = rm1 & 1;
  const int gi2 = t + 512,  r2 = gi2 / 68, rm2 = gi2 - r2 * 68, s2 = rm2 >> 1, ig2 = rm2 & 1;
  const int hg0 = h0 - 1 + r0, wg0 = w0 - 1 + s0;
  const int hg1 = h0 - 1 + r1, wg1 = w0 - 1 + s1;
  const int hg2 = h0 - 1 + r2, wg2 = w0 - 1 + s2;
  const bool va0 = (unsigned)hg0 < 128u && (unsigned)wg0 < 128u;
  const bool va1 = (unsigned)hg1 < 128u && (unsigned)wg1 < 128u;
  const bool va2 = t < 168 && (unsigned)hg2 < 128u && (unsigned)wg2 < 128u;
  const int gof0 = (hg0 * 128 + wg0) * 16 + ig0 * 8;
  const int gof1 = (hg1 * 128 + wg1) * 16 + ig1 * 8;
  const int gof2 = (hg2 * 128 + wg2) * 16 + ig2 * 8;
  const int io0 = (r0 * 34 + s0) * 16 + (ig0 ^ ((s0 >> 2) & 1)) * 8;
  const int io1 = (r1 * 34 + s1) * 16 + (ig1 ^ ((s1 >> 2) & 1)) * 8;
  const int io2 = (r2 * 34 + s2) * 16 + (ig2 ^ ((s2 >> 2) & 1)) * 8;

  // prologue: stage planes p=0..2 (global d = d0-1 .. d0+1) into slots 0..2
  #pragma unroll
  for (int p = 0; p < 3; ++p) {
    const int dg = d0 - 1 + p;
    const bool dv = (unsigned)dg < 64u;
    short8 v0 = {0,0,0,0,0,0,0,0}, v1 = {0,0,0,0,0,0,0,0}, v2 = {0,0,0,0,0,0,0,0};
    if (dv && va0) v0 = *(const short8*)(zb + dg * 262144 + gof0);
    if (dv && va1) v1 = *(const short8*)(zb + dg * 262144 + gof1);
    if (dv && va2) v2 = *(const short8*)(zb + dg * 262144 + gof2);
    *(short8*)(&lz[p * PLANE + io0]) = v0;
    *(short8*)(&lz[p * PLANE + io1]) = v1;
    if (t < 168) *(short8*)(&lz[p * PLANE + io2]) = v2;
  }
  __syncthreads();

  int sA = 0, sB = PLANE, sC = 2 * PLANE;   // slots of planes dl, dl+1, dl+2

  #pragma unroll 1
  for (int dl = 0; dl < DT; ++dl) {
    // T14 stage-issue: plane dl+3 (global d = d0+dl+2) -> will overwrite slot sA
    short8 sv0 = {0,0,0,0,0,0,0,0}, sv1 = {0,0,0,0,0,0,0,0}, sv2 = {0,0,0,0,0,0,0,0};
    const bool doStage = dl < DT - 1;
    if (doStage) {
      const int dg = d0 + dl + 2;
      const bool dv = (unsigned)dg < 64u;
      if (dv && va0) sv0 = *(const short8*)(zb + dg * 262144 + gof0);
      if (dv && va1) sv1 = *(const short8*)(zb + dg * 262144 + gof1);
      if (dv && va2) sv2 = *(const short8*)(zb + dg * 262144 + gof2);
    }
    // compute dl: 4 tiles per wave (hl = wid*2+(q>>1), wt = q&1), 14 MFMA each
    #pragma unroll
    for (int q = 0; q < 4; ++q) {
      const int hl = wid * 2 + (q >> 1), wt = q & 1;
      const int qb = (hl * 34 + wt * 16 + m) * 16 + icb;
      f32x4 acc = {0.f, 0.f, 0.f, 0.f};
      __builtin_amdgcn_s_setprio(1);
      #pragma unroll
      for (int cc = 0; cc < 14; ++cc) {
        const int kp0 = 2 * cc;
        const int kp1 = (2 * cc + 1 > 26) ? 26 : 2 * cc + 1;
        const int kd0 = kp0 / 9, kh0 = (kp0 % 9) / 3, kw0 = kp0 % 3;
        const int kd1 = kp1 / 9, kh1 = (kp1 % 9) / 3, kw1 = kp1 % 3;
        const int co0 = (kh0 * 34 + kw0) * 16;
        const int co1 = (kh1 * 34 + kw1) * 16;
        const int ba0 = (kd0 == 0) ? sA : (kd0 == 1) ? sB : sC;
        const int ba1 = (kd1 == 0) ? sA : (kd1 == 1) ? sB : sC;
        const int xk0 = (kw0 == 0) ? xw0 : (kw0 == 1) ? xw1 : xw2;
        const int xk1 = (kw1 == 0) ? xw0 : (kw1 == 1) ? xw1 : xw2;
        const int off0 = (qb ^ xk0) + co0 + ba0;
        const int off1 = (qb ^ xk1) + co1 + ba1;
        const int off = gs ? off1 : off0;
        short8 a = *(const short8*)(&lz[off]);
        acc = __builtin_amdgcn_mfma_f32_16x16x32_bf16(a, fb[cc], acc, 0, 0, 0);
      }
      __builtin_amdgcn_s_setprio(0);
      float* op = out + (((size_t)(b * 16 + m) * 64 + (d0 + dl)) * 128 + (h0 + hl)) * 128
                  + w0 + wt * 16 + g * 4;
      *(float4*)op = make_float4(acc[0], acc[1], acc[2], acc[3]);
    }
    __syncthreads();            // all waves done reading plane dl (slot sA)
    if (doStage) {
      *(short8*)(&lz[sA + io0]) = sv0;
      *(short8*)(&lz[sA + io1]) = sv1;
      if (t < 168) *(short8*)(&lz[sA + io2]) = sv2;
      __syncthreads();          // plane dl+3 visible before compute dl+1
    }
    const int tmp = sA; sA = sB; sB = sC; sC = tmp;
  }
}

__global__ void k5_hist_out(const int* __restrict__ hist, float* __restrict__ out) {
  int t = threadIdx.x;
  if (t < 21) out[33554432u + t] = (float)hist[t] * (100.0f / 33554432.0f);
}

extern "C" void kernel_launch(void* const* d_in, const int* in_sizes, int n_in,
                              void* d_out, int out_size, void* d_ws, size_t ws_size,
                              hipStream_t stream) {
  (void)in_sizes; (void)n_in; (void)out_size; (void)ws_size;
  const float* x   = (const float*)d_in[0];
  const float* gw  = (const float*)d_in[1];
  const float* gb  = (const float*)d_in[2];
  const float* thr = (const float*)d_in[3];
  const float* cw  = (const float*)d_in[4];
  float* out = (float*)d_out;

  char* ws = (char*)d_ws;
  unsigned short* z = (unsigned short*)ws;                            // 64 MiB bf16
  float2* partials = (float2*)(ws + (size_t)67108864);                // 8 KiB
  float2* stats    = (float2*)(ws + (size_t)67108864 + 8192);         // 128 B
  int*    hist     = (int*)  (ws + (size_t)67108864 + 8192 + 128);    // 84 B
  unsigned short* fbw = (unsigned short*)(ws + (size_t)67108864 + 16384); // 14336 B

  k1_partials<<<1024, 256, 0, stream>>>(x, partials);
  k2_stats<<<1, 64, 0, stream>>>(partials, stats, hist);
  k2b_wprep<<<1, 896, 0, stream>>>(cw, fbw);
  k3_norm_thresh_hist<<<1024, 256, 0, stream>>>(x, gw, gb, thr, stats, z, hist);
  k4_conv<<<dim3(64, 8, 2), 256, 0, stream>>>(z, fbw, out);
  k5_hist_out<<<1, 64, 0, stream>>>(hist, out);
}